// Round 8
// baseline (214.940 us; speedup 1.0000x reference)
//
#include <hip/hip_runtime.h>

#define B_TOT 65536
#define T_STEPS 10
#define D_IN 16
#define H 64
#define G4H 256
#define D_MLP 30
#define D_OUT 4
#define BTILE 32
#define PSTR 72     // h-plane row stride (shorts): 144B rows -> ds_read_b128 ALIGNED; 36dw -> 2-way only
#define DSTR 32     // d buffer row stride (shorts): 64B rows -> aligned + contiguous ad reads
#define LOG2E 1.44269504088896340736f
#define TWO_LOG2E 2.88539008177792681472f

typedef short short8 __attribute__((ext_vector_type(8)));
typedef float float4_t __attribute__((ext_vector_type(4)));
typedef __bf16 bf16x8_t __attribute__((ext_vector_type(8)));

static __device__ __forceinline__ short f2bf(float f) {  // round-half-up (activations)
    unsigned u = __builtin_bit_cast(unsigned, f);
    return (short)(unsigned short)((u + 0x8000u) >> 16);
}
static __device__ __forceinline__ short f2bf_rne(float f) {  // weights
    unsigned u = __builtin_bit_cast(unsigned, f);
    unsigned r = (u + 0x7FFFu + ((u >> 16) & 1u)) >> 16;
    return (short)(unsigned short)r;
}
static __device__ __forceinline__ float bf2f(short s) {
    unsigned u = ((unsigned)(unsigned short)s) << 16;
    return __builtin_bit_cast(float, u);
}
static __device__ __forceinline__ float4_t mfma16(short8 a, short8 b, float4_t c) {
    return __builtin_amdgcn_mfma_f32_16x16x32_bf16(
        __builtin_bit_cast(bf16x8_t, a), __builtin_bit_cast(bf16x8_t, b), c, 0, 0, 0);
}
// pack two f32 -> one dword of 2 bf16 (round-half-up, same bits as f2bf pairwise)
static __device__ __forceinline__ unsigned pk2bf(float lo, float hi) {
    const unsigned ulo = __builtin_bit_cast(unsigned, lo) + 0x8000u;
    const unsigned uhi = __builtin_bit_cast(unsigned, hi) + 0x8000u;
    return (ulo >> 16) | (uhi & 0xFFFF0000u);
}

// ---- workspace layout (bytes) ----
#define WS_WU1 0        // 48 frags x 1KB = 49152
#define WS_WU2 49152    // 48 frags = 49152
#define WS_WD  98304    // 4 frags = 4096
#define WS_BDP 102400   // 32 f32

// Weights pre-swizzled to MFMA B-frag order (frag f, lane l, elem e -> B[k=(l>>4)*8+e][n=l&15])
// and pre-scaled: i/f/o gates by log2e, L1 g-gate by 2*log2e, L2 g-gate (relu) raw.
// TRANSPOSE DUALITY (r7): the same register bits serve as an A-frag of U^T, so
// z^T = mfma(wz, h_frag) needs NO new layouts.
// BIAS FOLDING (r5): b1 in wu1 kt2 row k=16 (activated by 1.0 in ax); b2 in wu2 kt0 row
// k=30 (activated by d[...,30]==1.0 via bdp[30]=1.0).
// wu1: A1=[h1(0:64)|x(16)|1|0...], kt0=U1[0:32], kt1=U1[32:64], kt2=[W1(16);b1;zeros(15)]
// wu2: A2=[d(0:30)|1|0|h2(0:64)], kt0=[W2(30);b2;0], kt1=U2[0:32], kt2=U2[32:64]
// wd : d = h1 @ Wd (cols padded 30->32, col30 forced to 1.0 via bdp), unscaled
__global__ void precompute(const float* __restrict__ W1, const float* __restrict__ U1,
                           const float* __restrict__ b1, const float* __restrict__ Wd,
                           const float* __restrict__ bd, const float* __restrict__ W2,
                           const float* __restrict__ U2, const float* __restrict__ b2,
                           short* __restrict__ wu1_sw, short* __restrict__ wu2_sw,
                           short* __restrict__ wd_sw, float* __restrict__ bdp) {
    const int lane = threadIdx.x;  // 64
    const int b = blockIdx.x;      // 101
    if (b < 48) {
        const int f = b, jt = f / 12, g = (f / 3) & 3, kt = f % 3;
        const int col = g * 64 + jt * 16 + (lane & 15);
        const float sc = (g == 2) ? TWO_LOG2E : LOG2E;
        for (int e = 0; e < 8; ++e) {
            const int sub = (lane >> 4) * 8 + e;  // 0..31
            float v;
            if (kt == 0)      v = U1[sub * G4H + col];
            else if (kt == 1) v = U1[(sub + 32) * G4H + col];
            else              v = (sub < 16) ? W1[sub * G4H + col]
                                             : ((sub == 16) ? b1[col] : 0.0f);
            wu1_sw[(f * 64 + lane) * 8 + e] = f2bf_rne(v * sc);
        }
    } else if (b < 96) {
        const int f = b - 48, jt = f / 12, g = (f / 3) & 3, kt = f % 3;
        const int col = g * 64 + jt * 16 + (lane & 15);
        const float sc = (g == 2) ? 1.0f : LOG2E;  // relu gate stays raw
        for (int e = 0; e < 8; ++e) {
            const int sub = (lane >> 4) * 8 + e;
            float v;
            if (kt == 0)      v = (sub < D_MLP) ? W2[sub * G4H + col]
                                                : ((sub == D_MLP) ? b2[col] : 0.0f);
            else if (kt == 1) v = U2[sub * G4H + col];
            else              v = U2[(sub + 32) * G4H + col];
            wu2_sw[(f * 64 + lane) * 8 + e] = f2bf_rne(v * sc);
        }
    } else if (b < 100) {
        const int fd = b - 96, nt = fd >> 1, kt = fd & 1;
        const int col = nt * 16 + (lane & 15);
        for (int e = 0; e < 8; ++e) {
            const int k = kt * 32 + (lane >> 4) * 8 + e;  // h1 dim 0..63
            const float v = (col < D_MLP) ? Wd[k * D_MLP + col] : 0.0f;
            wd_sw[(fd * 64 + lane) * 8 + e] = f2bf_rne(v);
        }
    } else {
        // bdp: dense bias cols 0..29; col 30 = 1.0 (phase-2 bias activator); col 31 = 0
        if (lane < 32)
            bdp[lane] = (lane < D_MLP) ? bd[lane] : ((lane == D_MLP) ? 1.0f : 0.0f);
    }
}

// ---------------- fully fused: LSTM1 -> Dense(D in LDS) -> LSTM2 -> projection ----------------
// r8 OCCUPANCY RESTRUCTURE: 512-thread blocks (8 waves). waves 0-3 own batch rows 0-15,
// waves 4-7 rows 16-31 (m = wave>>2); gate-col slice by w4 = wave&3. Per-wave work halves;
// blocks/CU = min(LDS 5, threads 2048/512=4) = 4 -> 32 waves/CU = 8 waves/SIMD (HW cap),
// vs 20 waves/CU before. Evidence: r6 (+1 wave/SIMD = +5%), r7 (op-cut = null), VALUBusy
// stuck at 68% -> latency-bound, occupancy is the lever.
// Pressure drops: cc 8->4, single ax frag, NO cross-m shfl (each wave loads its own m's x),
// wd streaming on waves 0-3 only. d-proj: waves 0-3 (no extra barrier needed: next-t gate
// writes touch the other P plane). Phase-2 activation: single-rcp merge.
// TRIPWIRES: occupancy ~55 but dur flat -> barrier-bound; VGPR>64 / WRITE>>4MB -> revert.
__global__ __launch_bounds__(512)
__attribute__((amdgpu_waves_per_eu(4, 8)))
void lstm_all(const float* __restrict__ x, const short* __restrict__ wu1_sw,
              const short* __restrict__ wu2_sw, const short* __restrict__ wd_sw,
              const float* __restrict__ bdp, const float* __restrict__ Wf,
              const float* __restrict__ bfin, float* __restrict__ out) {
    __shared__ __align__(16) short P[2][BTILE * PSTR];        // 9216 B h-plane (dbuf)
    __shared__ __align__(16) short D[T_STEPS][BTILE * DSTR];  // 20480 B dense buffer
    // total 29696 B; 4 blocks/CU (thread-capped) = 32 waves/CU

    const int tid = threadIdx.x, lane = tid & 63, wave = tid >> 6;  // wave 0..7
    const int q = lane >> 4, n = lane & 15;
    const int m = wave >> 2;       // batch half: rows 16m..16m+15
    const int w4 = wave & 3;       // gate-col slice [g*64 + w4*16, +16)
    const int b0 = blockIdx.x * BTILE;

    // ---- phase-1 weights: slice by w4 ----
    short8 wz[4][3];
#pragma unroll
    for (int g = 0; g < 4; ++g)
#pragma unroll
        for (int kt = 0; kt < 3; ++kt)
            wz[g][kt] = ((const short8*)wu1_sw)[(w4 * 12 + g * 3 + kt) * 64 + lane];

    // d-projection: waves 0-3 -> tile (mw, ntw); wd frags re-loaded per-t (L2-hot)
    const int mw = (wave >> 1) & 1, ntw = wave & 1;
    const float bdv = bdp[ntw * 16 + n];

    // bias activator for the ax frag: q==2 lanes elem0 = bf16(1.0), else 0
    const unsigned bias0 = (q == 2) ? 0x00003F80u : 0u;

    for (int i = tid; i < BTILE * PSTR; i += 512) P[0][i] = 0;

    float4_t cc = (float4_t){0, 0, 0, 0};

    // x loads: q<2 lanes load their own m's row (b0+16m+n), k-half q. No cross-m shuffle.
    const float* xlane = x + (size_t)(b0 + 16 * m + n) * (T_STEPS * D_IN) + q * 8;
    float4 px0 = {0, 0, 0, 0}, px1 = {0, 0, 0, 0};
    if (q < 2) {
        px0 = *(const float4*)xlane;
        px1 = *(const float4*)(xlane + 4);
    }
    __syncthreads();  // P[0] zeros visible

    // ================= phase 1: LSTM1 (tanh) + Dense into D =================
    for (int t = 0; t < T_STEPS; ++t) {
        const short* cb = P[t & 1];
        short* nb = P[(t & 1) ^ 1];

        // wd frags: waves 0-3 only; opaque pointer defeats LICM -> live range ends at d-proj.
        short8 wda = {}, wdb = {};
        if (wave < 4) {
            const short8* wp = (const short8*)wd_sw + (ntw * 2) * 64 + lane;
            asm volatile("" : "+v"(wp));
            wda = wp[0];
            wdb = wp[64];
        }

        // x frag (B-operand = x^T in swapped MFMA); q>=2 lanes carry the bias pattern.
        uint4 axu = (uint4){bias0, 0u, 0u, 0u};
        if (q < 2) {
            axu.x = pk2bf(px0.x, px0.y);
            axu.y = pk2bf(px0.z, px0.w);
            axu.z = pk2bf(px1.x, px1.y);
            axu.w = pk2bf(px1.z, px1.w);
            const int tn = (t + 1 < T_STEPS) ? t + 1 : T_STEPS - 1;
            px0 = *(const float4*)(xlane + tn * D_IN);
            px1 = *(const float4*)(xlane + tn * D_IN + 4);
        }
        const short8 ax = __builtin_bit_cast(short8, axu);

        const int arow = (16 * m + n) * PSTR + q * 8;
        const short8 ah0 = *(const short8*)&cb[arow];
        const short8 ah1 = *(const short8*)&cb[arow + 32];
        float4_t ac[4];
#pragma unroll
        for (int g = 0; g < 4; ++g) {
            // SWAPPED operands: ac[g][jj] = gate g for cell (batch=16m+n, hcol=w4*16+q*4+jj)
            float4_t c = (float4_t){0, 0, 0, 0};
            c = mfma16(wz[g][0], ah0, c);
            c = mfma16(wz[g][1], ah1, c);
            c = mfma16(wz[g][2], ax, c);   // includes +b1 via k=16
            ac[g] = c;
        }
        // merged-rcp activation: 5 exp2 + 2 rcp per cell.
        float hv[4];
#pragma unroll
        for (int jj = 0; jj < 4; ++jj) {
            const float Bv = __builtin_amdgcn_exp2f(-ac[0][jj]);  // 2^-zi'
            const float Fv = __builtin_amdgcn_exp2f(-ac[1][jj]);  // 2^-zf'
            const float Qv = __builtin_amdgcn_exp2f(ac[2][jj]);   // 2^{zg''}
            const float Av = __builtin_amdgcn_exp2f(-ac[3][jj]);  // 2^-zo'
            const float uu = (1.0f + Bv) * (Qv + 1.0f);
            const float vv = 1.0f + Fv;
            const float num = cc[jj] * uu + (Qv - 1.0f) * vv;
            const float cn = num * __builtin_amdgcn_rcpf(uu * vv);
            cc[jj] = cn;
            const float Pv = __builtin_amdgcn_exp2f(cn * TWO_LOG2E);
            const float ww = (1.0f + Av) * (Pv + 1.0f);
            hv[jj] = (Pv - 1.0f) * __builtin_amdgcn_rcpf(ww);
        }
        // one packed 8B write: row 16m+n, cols w4*16+q*4..+3
        *(uint2*)&nb[(16 * m + n) * PSTR + w4 * 16 + q * 4] =
            (uint2){pk2bf(hv[0], hv[1]), pk2bf(hv[2], hv[3])};
        __syncthreads();  // h1_t complete (also drains wd/px loads)

        // d_t = h1_t @ Wd + bd -> D[t]: waves 0-3, one 16x16 tile each, k=64.
        // col 30 gets 0 + bdv(=1.0) -> exact 1.0 in bf16: the phase-2 bias activator.
        // No trailing barrier needed: waves 4-7's next-t writes go to the OTHER P plane.
        if (wave < 4) {
            const int drow = (16 * mw + n) * PSTR + q * 8;
            const short8 dh0 = *(const short8*)&nb[drow];
            const short8 dh1 = *(const short8*)&nb[drow + 32];
            float4_t dd = (float4_t){bdv, bdv, bdv, bdv};
            dd = mfma16(dh0, wda, dd);
            dd = mfma16(dh1, wdb, dd);
            short* dt = &D[t][0];
#pragma unroll
            for (int jj = 0; jj < 4; ++jj)
                dt[(16 * mw + q * 4 + jj) * DSTR + ntw * 16 + n] = f2bf(dd[jj]);
        }
    }

    // ================= phase boundary =================
    __syncthreads();  // D[9] writes + all P reads done before re-zeroing
#pragma unroll
    for (int g = 0; g < 4; ++g)
#pragma unroll
        for (int kt = 0; kt < 3; ++kt)
            wz[g][kt] = ((const short8*)wu2_sw)[(w4 * 12 + g * 3 + kt) * 64 + lane];
    cc = (float4_t){0, 0, 0, 0};
    for (int i = tid; i < BTILE * PSTR; i += 512) P[0][i] = 0;
    __syncthreads();

    // ================= phase 2: LSTM2 (relu) from D =================
    for (int t = 0; t < T_STEPS; ++t) {
        const short* cb = P[t & 1];
        short* nb = P[(t & 1) ^ 1];

        const int ar = 16 * m + n;
        const short8 ad  = *(const short8*)&D[t][ar * DSTR + q * 8];
        const short8 ah0 = *(const short8*)&cb[ar * PSTR + q * 8];
        const short8 ah1 = *(const short8*)&cb[ar * PSTR + 32 + q * 8];
        float4_t ac[4];
#pragma unroll
        for (int g = 0; g < 4; ++g) {
            // SWAPPED operands: ac[g][jj] = gate g for cell (batch=16m+n, hcol=w4*16+q*4+jj)
            float4_t c = (float4_t){0, 0, 0, 0};
            c = mfma16(wz[g][0], ad, c);       // includes +b2 via d[...,30]==1.0 x W2 row30
            c = mfma16(wz[g][1], ah0, c);
            c = mfma16(wz[g][2], ah1, c);
            ac[g] = c;
        }
        // single-rcp relu activation: 3 exp2 + 1 rcp per cell.
        // R = rcp(den*(1+A)); cn = num*(1+A)*R; h = max(num,0)*R.
        float hv[4];
#pragma unroll
        for (int jj = 0; jj < 4; ++jj) {
            const float Bv = __builtin_amdgcn_exp2f(-ac[0][jj]);
            const float Fv = __builtin_amdgcn_exp2f(-ac[1][jj]);
            const float gp = fmaxf(ac[2][jj], 0.0f);   // raw (unscaled) gate
            const float Av = __builtin_amdgcn_exp2f(-ac[3][jj]);
            const float eb = 1.0f + Bv, ef = 1.0f + Fv, ea = 1.0f + Av;
            const float num = cc[jj] * eb + gp * ef;
            const float R = __builtin_amdgcn_rcpf(eb * ef * ea);
            cc[jj] = num * ea * R;
            hv[jj] = fmaxf(num, 0.0f) * R;
        }
        *(uint2*)&nb[ar * PSTR + w4 * 16 + q * 4] =
            (uint2){pk2bf(hv[0], hv[1]), pk2bf(hv[2], hv[3])};
        __syncthreads();
    }

    // ---- out = h2_9 @ Wf + bf ; t=9 wrote nb = P[0] ----
    if (tid < 128) {
        const int r = tid >> 2, c = tid & 3;
        float s = bfin[c];
#pragma unroll
        for (int kb = 0; kb < 8; ++kb) {
            const short8 h8 = *(const short8*)&P[0][r * PSTR + kb * 8];
#pragma unroll
            for (int e = 0; e < 8; ++e)
                s += bf2f(h8[e]) * Wf[(kb * 8 + e) * D_OUT + c];
        }
        out[(size_t)(b0 + r) * D_OUT + c] = s;
    }
}

extern "C" void kernel_launch(void* const* d_in, const int* in_sizes, int n_in,
                              void* d_out, int out_size, void* d_ws, size_t ws_size,
                              hipStream_t stream) {
    const float* x  = (const float*)d_in[0];
    const float* W1 = (const float*)d_in[1];
    const float* U1 = (const float*)d_in[2];
    const float* b1 = (const float*)d_in[3];
    const float* Wd = (const float*)d_in[4];
    const float* bd = (const float*)d_in[5];
    const float* W2 = (const float*)d_in[6];
    const float* U2 = (const float*)d_in[7];
    const float* b2 = (const float*)d_in[8];
    const float* Wf = (const float*)d_in[9];
    const float* bf = (const float*)d_in[10];
    float* out = (float*)d_out;

    char* ws = (char*)d_ws;
    short* wu1_sw = (short*)(ws + WS_WU1);
    short* wu2_sw = (short*)(ws + WS_WU2);
    short* wd_sw  = (short*)(ws + WS_WD);
    float* bdp    = (float*)(ws + WS_BDP);

    precompute<<<101, 64, 0, stream>>>(W1, U1, b1, Wd, bd, W2, U2, b2,
                                       wu1_sw, wu2_sw, wd_sw, bdp);
    lstm_all<<<B_TOT / BTILE, 512, 0, stream>>>(x, wu1_sw, wu2_sw, wd_sw,
                                                bdp, Wf, bf, out);
}

// Round 9
// 193.559 us; speedup vs baseline: 1.1105x; 1.1105x over previous
//
#include <hip/hip_runtime.h>

#define B_TOT 65536
#define T_STEPS 10
#define D_IN 16
#define H 64
#define G4H 256
#define D_MLP 30
#define D_OUT 4
#define BTILE 32
#define PSTR 72     // h-plane row stride (shorts): 144B rows -> ds_read_b128 ALIGNED; 36dw -> 2-way only
#define DSTR 32     // d buffer row stride (shorts): 64B rows -> aligned + contiguous ad reads
#define LOG2E 1.44269504088896340736f
#define TWO_LOG2E 2.88539008177792681472f

typedef short short8 __attribute__((ext_vector_type(8)));
typedef float float4_t __attribute__((ext_vector_type(4)));
typedef __bf16 bf16x8_t __attribute__((ext_vector_type(8)));

static __device__ __forceinline__ short f2bf(float f) {  // round-half-up (activations)
    unsigned u = __builtin_bit_cast(unsigned, f);
    return (short)(unsigned short)((u + 0x8000u) >> 16);
}
static __device__ __forceinline__ short f2bf_rne(float f) {  // weights
    unsigned u = __builtin_bit_cast(unsigned, f);
    unsigned r = (u + 0x7FFFu + ((u >> 16) & 1u)) >> 16;
    return (short)(unsigned short)r;
}
static __device__ __forceinline__ float bf2f(short s) {
    unsigned u = ((unsigned)(unsigned short)s) << 16;
    return __builtin_bit_cast(float, u);
}
static __device__ __forceinline__ float4_t mfma16(short8 a, short8 b, float4_t c) {
    return __builtin_amdgcn_mfma_f32_16x16x32_bf16(
        __builtin_bit_cast(bf16x8_t, a), __builtin_bit_cast(bf16x8_t, b), c, 0, 0, 0);
}
// pack two f32 -> one dword of 2 bf16 (round-half-up, same bits as f2bf pairwise)
static __device__ __forceinline__ unsigned pk2bf(float lo, float hi) {
    const unsigned ulo = __builtin_bit_cast(unsigned, lo) + 0x8000u;
    const unsigned uhi = __builtin_bit_cast(unsigned, hi) + 0x8000u;
    return (ulo >> 16) | (uhi & 0xFFFF0000u);
}

// ---- workspace layout (bytes) ----
#define WS_WU1 0        // 48 frags x 1KB = 49152
#define WS_WU2 49152    // 48 frags = 49152
#define WS_WD  98304    // 4 frags = 4096
#define WS_BDP 102400   // 32 f32
#define WS_DG  114688   // global D buffer: 2048 blocks x 20480 B = 41,943,040
#define DG_PER_BLOCK (T_STEPS * BTILE * DSTR)            // shorts
#define DG_BYTES ((size_t)(B_TOT / BTILE) * DG_PER_BLOCK * 2)

// Weights pre-swizzled to MFMA B-frag order (frag f, lane l, elem e -> B[k=(l>>4)*8+e][n=l&15])
// and pre-scaled: i/f/o gates by log2e, L1 g-gate by 2*log2e, L2 g-gate (relu) raw.
// TRANSPOSE DUALITY (r7): the same register bits serve as an A-frag of U^T, so
// z^T = mfma(wz, h_frag) needs NO new layouts (and d^T = mfma(wd, h_frag) likewise, r9).
// BIAS FOLDING (r5): b1 in wu1 kt2 row k=16 (activated by 1.0 in ax); b2 in wu2 kt0 row
// k=30 (activated by d[...,30]==1.0 via bdp[30]=1.0).
// wu1: A1=[h1(0:64)|x(16)|1|0...], kt0=U1[0:32], kt1=U1[32:64], kt2=[W1(16);b1;zeros(15)]
// wu2: A2=[d(0:30)|1|0|h2(0:64)], kt0=[W2(30);b2;0], kt1=U2[0:32], kt2=U2[32:64]
// wd : d = h1 @ Wd (cols padded 30->32, col30 forced to 1.0 via bdp), unscaled
__global__ void precompute(const float* __restrict__ W1, const float* __restrict__ U1,
                           const float* __restrict__ b1, const float* __restrict__ Wd,
                           const float* __restrict__ bd, const float* __restrict__ W2,
                           const float* __restrict__ U2, const float* __restrict__ b2,
                           short* __restrict__ wu1_sw, short* __restrict__ wu2_sw,
                           short* __restrict__ wd_sw, float* __restrict__ bdp) {
    const int lane = threadIdx.x;  // 64
    const int b = blockIdx.x;      // 101
    if (b < 48) {
        const int f = b, jt = f / 12, g = (f / 3) & 3, kt = f % 3;
        const int col = g * 64 + jt * 16 + (lane & 15);
        const float sc = (g == 2) ? TWO_LOG2E : LOG2E;
        for (int e = 0; e < 8; ++e) {
            const int sub = (lane >> 4) * 8 + e;  // 0..31
            float v;
            if (kt == 0)      v = U1[sub * G4H + col];
            else if (kt == 1) v = U1[(sub + 32) * G4H + col];
            else              v = (sub < 16) ? W1[sub * G4H + col]
                                             : ((sub == 16) ? b1[col] : 0.0f);
            wu1_sw[(f * 64 + lane) * 8 + e] = f2bf_rne(v * sc);
        }
    } else if (b < 96) {
        const int f = b - 48, jt = f / 12, g = (f / 3) & 3, kt = f % 3;
        const int col = g * 64 + jt * 16 + (lane & 15);
        const float sc = (g == 2) ? 1.0f : LOG2E;  // relu gate stays raw
        for (int e = 0; e < 8; ++e) {
            const int sub = (lane >> 4) * 8 + e;
            float v;
            if (kt == 0)      v = (sub < D_MLP) ? W2[sub * G4H + col]
                                                : ((sub == D_MLP) ? b2[col] : 0.0f);
            else if (kt == 1) v = U2[sub * G4H + col];
            else              v = U2[(sub + 32) * G4H + col];
            wu2_sw[(f * 64 + lane) * 8 + e] = f2bf_rne(v * sc);
        }
    } else if (b < 100) {
        const int fd = b - 96, nt = fd >> 1, kt = fd & 1;
        const int col = nt * 16 + (lane & 15);
        for (int e = 0; e < 8; ++e) {
            const int k = kt * 32 + (lane >> 4) * 8 + e;  // h1 dim 0..63
            const float v = (col < D_MLP) ? Wd[k * D_MLP + col] : 0.0f;
            wd_sw[(fd * 64 + lane) * 8 + e] = f2bf_rne(v);
        }
    } else {
        // bdp: dense bias cols 0..29; col 30 = 1.0 (phase-2 bias activator); col 31 = 0
        if (lane < 32)
            bdp[lane] = (lane < D_MLP) ? bd[lane] : ((lane == D_MLP) ? 1.0f : 0.0f);
    }
}

// ---------------- r9 MAIN: D buffer in GLOBAL (L2-resident) -> LDS 9216 B ----------------
// Evidence chain: r6/r7 best = 110us @ 5 blocks/CU (LDS-capped), VALU 68% + MFMA 26% = 94%
// combined issue but 32% VALU idle; r4/r8 prove VGPR<=64 spill-free is unreachable (natural
// live ~66-75). So: evict D (20KB, the LDS bulk) to workspace -> LDS 9216 -> block cap by
// VGPR tier. waves_per_eu(4,6): budget ~85 fits natural live (NO spill) -> 6 blocks/CU
// = 24 waves/CU (+20% vs 20). D traffic (40MB w + 40MB r) is L2-class; phase-2 reads are
// 16B/lane fully coalesced; d-proj operand-swapped (transpose duality) so writes coalesce
// as dwordx2. Phase-2 uses r8-validated single-rcp merge.
__global__ __launch_bounds__(256)
__attribute__((amdgpu_waves_per_eu(4, 6)))
void lstm_all_g(const float* __restrict__ x, const short* __restrict__ wu1_sw,
                const short* __restrict__ wu2_sw, const short* __restrict__ wd_sw,
                const float* __restrict__ bdp, const float* __restrict__ Wf,
                const float* __restrict__ bfin, short* __restrict__ Dg,
                float* __restrict__ out) {
    __shared__ __align__(16) short P[2][BTILE * PSTR];  // 9216 B total
    const int tid = threadIdx.x, lane = tid & 63, wave = tid >> 6;
    const int q = lane >> 4, n = lane & 15;
    const int b0 = blockIdx.x * BTILE;
    short* const dgb = Dg + (size_t)blockIdx.x * DG_PER_BLOCK;

    // ---- phase-1 weights: wave owns gate-col slice [g*64 + wave*16, +16) ----
    short8 wz[4][3];
#pragma unroll
    for (int g = 0; g < 4; ++g)
#pragma unroll
        for (int kt = 0; kt < 3; ++kt)
            wz[g][kt] = ((const short8*)wu1_sw)[(wave * 12 + g * 3 + kt) * 64 + lane];

    // d-projection: wave -> (row-tile mw, col-tile ntw). Transposed output -> per-jj bias.
    const int mw = (wave >> 1) & 1, ntw = wave & 1;
    const float4 bdvv = *(const float4*)&bdp[ntw * 16 + q * 4];

    // bias activator for the ax frag: lanes 32..47 (q==2) elem0 = bf16(1.0), else 0
    const unsigned bias0 = (lane >= 32 && lane < 48) ? 0x00003F80u : 0u;
    const bool hb = (lane >= 32);

    for (int i = tid; i < BTILE * PSTR; i += 256) P[0][i] = 0;

    float4_t cc[2];
    cc[0] = (float4_t){0, 0, 0, 0};
    cc[1] = (float4_t){0, 0, 0, 0};

    // x loads, lane-packed: lane<32 -> m=0 rows (b0+n), lane>=32 -> m=1 rows (b0+16+n)
    const float* xlane = x + (size_t)(b0 + (lane >> 5) * 16 + n) * (T_STEPS * D_IN)
                           + ((lane >> 4) & 1) * 8;
    float4 px0 = *(const float4*)xlane;
    float4 px1 = *(const float4*)(xlane + 4);
    __syncthreads();  // P[0] zeros visible

    // ================= phase 1: LSTM1 (tanh) + Dense into Dg =================
    for (int t = 0; t < T_STEPS; ++t) {
        const short* cb = P[t & 1];
        short* nb = P[(t & 1) ^ 1];

        // wd frags: opaque pointer defeats LICM -> re-loaded each t (L2-hot), short live range
        const short8* wp = (const short8*)wd_sw + (ntw * 2) * 64 + lane;
        asm volatile("" : "+v"(wp));
        const short8 wda = wp[0];
        const short8 wdb = wp[64];

        // x frags; lanes>=32 masked to the bias pattern (1.0 at k=16 for q==2)
        uint4 axu;
        axu.x = pk2bf(px0.x, px0.y);
        axu.y = pk2bf(px0.z, px0.w);
        axu.z = pk2bf(px1.x, px1.y);
        axu.w = pk2bf(px1.z, px1.w);
        uint4 axv;
        axv.x = __shfl_xor((int)axu.x, 32);
        axv.y = __shfl_xor((int)axu.y, 32);
        axv.z = __shfl_xor((int)axu.z, 32);
        axv.w = __shfl_xor((int)axu.w, 32);
        const uint4 bmask = (uint4){bias0, 0u, 0u, 0u};
        short8 axm[2];
        axm[0] = __builtin_bit_cast(short8, hb ? bmask : axu);
        axm[1] = __builtin_bit_cast(short8, hb ? bmask : axv);

        const int tn = (t + 1 < T_STEPS) ? t + 1 : T_STEPS - 1;
        px0 = *(const float4*)(xlane + tn * D_IN);
        px1 = *(const float4*)(xlane + tn * D_IN + 4);

#pragma unroll
        for (int m = 0; m < 2; ++m) {
            const int arow = (16 * m + n) * PSTR + q * 8;
            const short8 ah0 = *(const short8*)&cb[arow];
            const short8 ah1 = *(const short8*)&cb[arow + 32];
            float4_t ac[4];
#pragma unroll
            for (int g = 0; g < 4; ++g) {
                // SWAPPED: ac[g][jj] = gate g of cell (batch=16m+n, hcol=wave*16+q*4+jj)
                float4_t c = (float4_t){0, 0, 0, 0};
                c = mfma16(wz[g][0], ah0, c);
                c = mfma16(wz[g][1], ah1, c);
                c = mfma16(wz[g][2], axm[m], c);   // includes +b1 via k=16
                ac[g] = c;
            }
            // merged-rcp activation: 5 exp2 + 2 rcp per cell.
            float hv[4];
#pragma unroll
            for (int jj = 0; jj < 4; ++jj) {
                const float Bv = __builtin_amdgcn_exp2f(-ac[0][jj]);
                const float Fv = __builtin_amdgcn_exp2f(-ac[1][jj]);
                const float Qv = __builtin_amdgcn_exp2f(ac[2][jj]);
                const float Av = __builtin_amdgcn_exp2f(-ac[3][jj]);
                const float uu = (1.0f + Bv) * (Qv + 1.0f);
                const float vv = 1.0f + Fv;
                const float num = cc[m][jj] * uu + (Qv - 1.0f) * vv;
                const float cn = num * __builtin_amdgcn_rcpf(uu * vv);
                cc[m][jj] = cn;
                const float Pv = __builtin_amdgcn_exp2f(cn * TWO_LOG2E);
                const float ww = (1.0f + Av) * (Pv + 1.0f);
                hv[jj] = (Pv - 1.0f) * __builtin_amdgcn_rcpf(ww);
            }
            *(uint2*)&nb[(16 * m + n) * PSTR + wave * 16 + q * 4] =
                (uint2){pk2bf(hv[0], hv[1]), pk2bf(hv[2], hv[3])};
        }
        __syncthreads();  // h1_t complete

        // d_t^T = mfma(wd, h) (transpose duality: same frag bits). Thread holds d-cols
        // ntw*16+q*4..+3 of batch row 16mw+n -> coalesced dwordx2 store to Dg.
        // dcol 30 gets 0 + 1.0 (bdvv) -> exact bf16 1.0: the phase-2 bias activator.
        {
            const int drow = (16 * mw + n) * PSTR + q * 8;
            const short8 dh0 = *(const short8*)&nb[drow];
            const short8 dh1 = *(const short8*)&nb[drow + 32];
            float4_t dd = (float4_t){bdvv.x, bdvv.y, bdvv.z, bdvv.w};
            dd = mfma16(wda, dh0, dd);
            dd = mfma16(wdb, dh1, dd);
            short* dgt = dgb + t * (BTILE * DSTR);
            *(uint2*)&dgt[(16 * mw + n) * DSTR + ntw * 16 + q * 4] =
                (uint2){pk2bf(dd[0], dd[1]), pk2bf(dd[2], dd[3])};
        }
    }

    // ================= phase boundary =================
    __syncthreads();  // drains Dg stores (vmcnt) + all P reads before re-zeroing
#pragma unroll
    for (int g = 0; g < 4; ++g)
#pragma unroll
        for (int kt = 0; kt < 3; ++kt)
            wz[g][kt] = ((const short8*)wu2_sw)[(wave * 12 + g * 3 + kt) * 64 + lane];
    cc[0] = (float4_t){0, 0, 0, 0};
    cc[1] = (float4_t){0, 0, 0, 0};
    for (int i = tid; i < BTILE * PSTR; i += 256) P[0][i] = 0;
    __syncthreads();

    // ================= phase 2: LSTM2 (relu) from Dg =================
    for (int t = 0; t < T_STEPS; ++t) {
        const short* cb = P[t & 1];
        short* nb = P[(t & 1) ^ 1];

        // both m rows' d frags issued together (independent, L2-hot, 16B/lane coalesced)
        const short* dgt = dgb + t * (BTILE * DSTR);
        const uint4 adu0 = *(const uint4*)&dgt[n * DSTR + q * 8];
        const uint4 adu1 = *(const uint4*)&dgt[(16 + n) * DSTR + q * 8];
        short8 adm[2];
        adm[0] = __builtin_bit_cast(short8, adu0);
        adm[1] = __builtin_bit_cast(short8, adu1);

#pragma unroll
        for (int m = 0; m < 2; ++m) {
            const int ar = 16 * m + n;
            const short8 ah0 = *(const short8*)&cb[ar * PSTR + q * 8];
            const short8 ah1 = *(const short8*)&cb[ar * PSTR + 32 + q * 8];
            float4_t ac[4];
#pragma unroll
            for (int g = 0; g < 4; ++g) {
                float4_t c = (float4_t){0, 0, 0, 0};
                c = mfma16(wz[g][0], adm[m], c);   // includes +b2 via dcol30==1.0 x W2 row30
                c = mfma16(wz[g][1], ah0, c);
                c = mfma16(wz[g][2], ah1, c);
                ac[g] = c;
            }
            // single-rcp relu activation (r8-validated): 3 exp2 + 1 rcp per cell.
            float hv[4];
#pragma unroll
            for (int jj = 0; jj < 4; ++jj) {
                const float Bv = __builtin_amdgcn_exp2f(-ac[0][jj]);
                const float Fv = __builtin_amdgcn_exp2f(-ac[1][jj]);
                const float gp = fmaxf(ac[2][jj], 0.0f);
                const float Av = __builtin_amdgcn_exp2f(-ac[3][jj]);
                const float eb = 1.0f + Bv, ef = 1.0f + Fv, ea = 1.0f + Av;
                const float num = cc[m][jj] * eb + gp * ef;
                const float R = __builtin_amdgcn_rcpf(eb * ef * ea);
                cc[m][jj] = num * ea * R;
                hv[jj] = fmaxf(num, 0.0f) * R;
            }
            *(uint2*)&nb[ar * PSTR + wave * 16 + q * 4] =
                (uint2){pk2bf(hv[0], hv[1]), pk2bf(hv[2], hv[3])};
        }
        __syncthreads();
    }

    // ---- out = h2_9 @ Wf + bf ; t=9 wrote nb = P[0] ----
    if (tid < 128) {
        const int r = tid >> 2, c = tid & 3;
        float s = bfin[c];
#pragma unroll
        for (int kb = 0; kb < 8; ++kb) {
            const short8 h8 = *(const short8*)&P[0][r * PSTR + kb * 8];
#pragma unroll
            for (int e = 0; e < 8; ++e)
                s += bf2f(h8[e]) * Wf[(kb * 8 + e) * D_OUT + c];
        }
        out[(size_t)(b0 + r) * D_OUT + c] = s;
    }
}

// ---------------- FALLBACK (r7 verbatim, proven 110us): D in LDS ----------------
__global__ __launch_bounds__(256)
__attribute__((amdgpu_waves_per_eu(4, 8)))
void lstm_all_lds(const float* __restrict__ x, const short* __restrict__ wu1_sw,
                  const short* __restrict__ wu2_sw, const short* __restrict__ wd_sw,
                  const float* __restrict__ bdp, const float* __restrict__ Wf,
                  const float* __restrict__ bfin, float* __restrict__ out) {
    __shared__ __align__(16) short P[2][BTILE * PSTR];
    __shared__ __align__(16) short D[T_STEPS][BTILE * DSTR];
    const int tid = threadIdx.x, lane = tid & 63, wave = tid >> 6;
    const int q = lane >> 4, n = lane & 15;
    const int b0 = blockIdx.x * BTILE;

    short8 wz[4][3];
#pragma unroll
    for (int g = 0; g < 4; ++g)
#pragma unroll
        for (int kt = 0; kt < 3; ++kt)
            wz[g][kt] = ((const short8*)wu1_sw)[(wave * 12 + g * 3 + kt) * 64 + lane];
    const int mw = wave >> 1, ntw = wave & 1;
    const float bdv = bdp[ntw * 16 + n];
    const unsigned bias0 = (lane >= 32 && lane < 48) ? 0x00003F80u : 0u;
    const bool hb = (lane >= 32);
    for (int i = tid; i < BTILE * PSTR; i += 256) P[0][i] = 0;
    float4_t cc[2];
    cc[0] = (float4_t){0, 0, 0, 0};
    cc[1] = (float4_t){0, 0, 0, 0};
    const float* xlane = x + (size_t)(b0 + (lane >> 5) * 16 + n) * (T_STEPS * D_IN)
                           + ((lane >> 4) & 1) * 8;
    float4 px0 = *(const float4*)xlane;
    float4 px1 = *(const float4*)(xlane + 4);
    __syncthreads();

    for (int t = 0; t < T_STEPS; ++t) {
        const short* cb = P[t & 1];
        short* nb = P[(t & 1) ^ 1];
        const short8* wp = (const short8*)wd_sw + (ntw * 2) * 64 + lane;
        asm volatile("" : "+v"(wp));
        const short8 wda = wp[0];
        const short8 wdb = wp[64];
        uint4 axu;
        axu.x = pk2bf(px0.x, px0.y);
        axu.y = pk2bf(px0.z, px0.w);
        axu.z = pk2bf(px1.x, px1.y);
        axu.w = pk2bf(px1.z, px1.w);
        uint4 axv;
        axv.x = __shfl_xor((int)axu.x, 32);
        axv.y = __shfl_xor((int)axu.y, 32);
        axv.z = __shfl_xor((int)axu.z, 32);
        axv.w = __shfl_xor((int)axu.w, 32);
        const uint4 bmask = (uint4){bias0, 0u, 0u, 0u};
        short8 axm[2];
        axm[0] = __builtin_bit_cast(short8, hb ? bmask : axu);
        axm[1] = __builtin_bit_cast(short8, hb ? bmask : axv);
        const int tn = (t + 1 < T_STEPS) ? t + 1 : T_STEPS - 1;
        px0 = *(const float4*)(xlane + tn * D_IN);
        px1 = *(const float4*)(xlane + tn * D_IN + 4);
#pragma unroll
        for (int m = 0; m < 2; ++m) {
            const int arow = (16 * m + n) * PSTR + q * 8;
            const short8 ah0 = *(const short8*)&cb[arow];
            const short8 ah1 = *(const short8*)&cb[arow + 32];
            float4_t ac[4];
#pragma unroll
            for (int g = 0; g < 4; ++g) {
                float4_t c = (float4_t){0, 0, 0, 0};
                c = mfma16(wz[g][0], ah0, c);
                c = mfma16(wz[g][1], ah1, c);
                c = mfma16(wz[g][2], axm[m], c);
                ac[g] = c;
            }
            float hv[4];
#pragma unroll
            for (int jj = 0; jj < 4; ++jj) {
                const float Bv = __builtin_amdgcn_exp2f(-ac[0][jj]);
                const float Fv = __builtin_amdgcn_exp2f(-ac[1][jj]);
                const float Qv = __builtin_amdgcn_exp2f(ac[2][jj]);
                const float Av = __builtin_amdgcn_exp2f(-ac[3][jj]);
                const float uu = (1.0f + Bv) * (Qv + 1.0f);
                const float vv = 1.0f + Fv;
                const float num = cc[m][jj] * uu + (Qv - 1.0f) * vv;
                const float cn = num * __builtin_amdgcn_rcpf(uu * vv);
                cc[m][jj] = cn;
                const float Pv = __builtin_amdgcn_exp2f(cn * TWO_LOG2E);
                const float ww = (1.0f + Av) * (Pv + 1.0f);
                hv[jj] = (Pv - 1.0f) * __builtin_amdgcn_rcpf(ww);
            }
            *(uint2*)&nb[(16 * m + n) * PSTR + wave * 16 + q * 4] =
                (uint2){pk2bf(hv[0], hv[1]), pk2bf(hv[2], hv[3])};
        }
        __syncthreads();
        {
            const int drow = (16 * mw + n) * PSTR + q * 8;
            const short8 dh0 = *(const short8*)&nb[drow];
            const short8 dh1 = *(const short8*)&nb[drow + 32];
            float4_t dd = (float4_t){bdv, bdv, bdv, bdv};
            dd = mfma16(dh0, wda, dd);
            dd = mfma16(dh1, wdb, dd);
            short* dt = &D[t][0];
#pragma unroll
            for (int jj = 0; jj < 4; ++jj)
                dt[(16 * mw + q * 4 + jj) * DSTR + ntw * 16 + n] = f2bf(dd[jj]);
        }
    }

    __syncthreads();
#pragma unroll
    for (int g = 0; g < 4; ++g)
#pragma unroll
        for (int kt = 0; kt < 3; ++kt)
            wz[g][kt] = ((const short8*)wu2_sw)[(wave * 12 + g * 3 + kt) * 64 + lane];
    cc[0] = (float4_t){0, 0, 0, 0};
    cc[1] = (float4_t){0, 0, 0, 0};
    for (int i = tid; i < BTILE * PSTR; i += 256) P[0][i] = 0;
    __syncthreads();

    for (int t = 0; t < T_STEPS; ++t) {
        const short* cb = P[t & 1];
        short* nb = P[(t & 1) ^ 1];
#pragma unroll
        for (int m = 0; m < 2; ++m) {
            const int ar = 16 * m + n;
            const short8 ad  = *(const short8*)&D[t][ar * DSTR + q * 8];
            const short8 ah0 = *(const short8*)&cb[ar * PSTR + q * 8];
            const short8 ah1 = *(const short8*)&cb[ar * PSTR + 32 + q * 8];
            float4_t ac[4];
#pragma unroll
            for (int g = 0; g < 4; ++g) {
                float4_t c = (float4_t){0, 0, 0, 0};
                c = mfma16(wz[g][0], ad, c);
                c = mfma16(wz[g][1], ah0, c);
                c = mfma16(wz[g][2], ah1, c);
                ac[g] = c;
            }
            float hv[4];
#pragma unroll
            for (int jj = 0; jj < 4; ++jj) {
                const float Bv = __builtin_amdgcn_exp2f(-ac[0][jj]);
                const float Fv = __builtin_amdgcn_exp2f(-ac[1][jj]);
                const float gp = fmaxf(ac[2][jj], 0.0f);
                const float Av = __builtin_amdgcn_exp2f(-ac[3][jj]);
                const float eb = 1.0f + Bv, ef = 1.0f + Fv, ea = 1.0f + Av;
                const float num = cc[m][jj] * eb + gp * ef;
                const float R = __builtin_amdgcn_rcpf(eb * ef * ea);
                cc[m][jj] = num * ea * R;
                hv[jj] = fmaxf(num, 0.0f) * R;
            }
            *(uint2*)&nb[ar * PSTR + wave * 16 + q * 4] =
                (uint2){pk2bf(hv[0], hv[1]), pk2bf(hv[2], hv[3])};
        }
        __syncthreads();
    }

    if (tid < 128) {
        const int r = tid >> 2, c = tid & 3;
        float s = bfin[c];
#pragma unroll
        for (int kb = 0; kb < 8; ++kb) {
            const short8 h8 = *(const short8*)&P[0][r * PSTR + kb * 8];
#pragma unroll
            for (int e = 0; e < 8; ++e)
                s += bf2f(h8[e]) * Wf[(kb * 8 + e) * D_OUT + c];
        }
        out[(size_t)(b0 + r) * D_OUT + c] = s;
    }
}

extern "C" void kernel_launch(void* const* d_in, const int* in_sizes, int n_in,
                              void* d_out, int out_size, void* d_ws, size_t ws_size,
                              hipStream_t stream) {
    const float* x  = (const float*)d_in[0];
    const float* W1 = (const float*)d_in[1];
    const float* U1 = (const float*)d_in[2];
    const float* b1 = (const float*)d_in[3];
    const float* Wd = (const float*)d_in[4];
    const float* bd = (const float*)d_in[5];
    const float* W2 = (const float*)d_in[6];
    const float* U2 = (const float*)d_in[7];
    const float* b2 = (const float*)d_in[8];
    const float* Wf = (const float*)d_in[9];
    const float* bf = (const float*)d_in[10];
    float* out = (float*)d_out;

    char* ws = (char*)d_ws;
    short* wu1_sw = (short*)(ws + WS_WU1);
    short* wu2_sw = (short*)(ws + WS_WU2);
    short* wd_sw  = (short*)(ws + WS_WD);
    float* bdp    = (float*)(ws + WS_BDP);

    precompute<<<101, 64, 0, stream>>>(W1, U1, b1, Wd, bd, W2, U2, b2,
                                       wu1_sw, wu2_sw, wd_sw, bdp);
    if (ws_size >= (size_t)WS_DG + DG_BYTES) {
        short* Dg = (short*)(ws + WS_DG);
        lstm_all_g<<<B_TOT / BTILE, 256, 0, stream>>>(x, wu1_sw, wu2_sw, wd_sw,
                                                      bdp, Wf, bf, Dg, out);
    } else {
        lstm_all_lds<<<B_TOT / BTILE, 256, 0, stream>>>(x, wu1_sw, wu2_sw, wd_sw,
                                                        bdp, Wf, bf, out);
    }
}

// Round 10
// 190.924 us; speedup vs baseline: 1.1258x; 1.0138x over previous
//
#include <hip/hip_runtime.h>

#define B_TOT 65536
#define T_STEPS 10
#define D_IN 16
#define H 64
#define G4H 256
#define D_MLP 30
#define D_OUT 4
#define BTILE 32
#define PSTR 72     // h-plane row stride (shorts): 144B rows -> ds_read_b128 ALIGNED; 36dw -> 2-way only
#define DSTR 32     // d buffer row stride (shorts): 64B rows -> aligned + contiguous ad reads
#define LOG2E 1.44269504088896340736f
#define TWO_LOG2E 2.88539008177792681472f

typedef short short8 __attribute__((ext_vector_type(8)));
typedef float float4_t __attribute__((ext_vector_type(4)));
typedef __bf16 bf16x8_t __attribute__((ext_vector_type(8)));

static __device__ __forceinline__ short f2bf(float f) {  // round-half-up (activations)
    unsigned u = __builtin_bit_cast(unsigned, f);
    return (short)(unsigned short)((u + 0x8000u) >> 16);
}
static __device__ __forceinline__ short f2bf_rne(float f) {  // weights
    unsigned u = __builtin_bit_cast(unsigned, f);
    unsigned r = (u + 0x7FFFu + ((u >> 16) & 1u)) >> 16;
    return (short)(unsigned short)r;
}
static __device__ __forceinline__ float bf2f(short s) {
    unsigned u = ((unsigned)(unsigned short)s) << 16;
    return __builtin_bit_cast(float, u);
}
static __device__ __forceinline__ float4_t mfma16(short8 a, short8 b, float4_t c) {
    return __builtin_amdgcn_mfma_f32_16x16x32_bf16(
        __builtin_bit_cast(bf16x8_t, a), __builtin_bit_cast(bf16x8_t, b), c, 0, 0, 0);
}
// pack two f32 -> one dword of 2 bf16 (round-half-up, same bits as f2bf pairwise)
static __device__ __forceinline__ unsigned pk2bf(float lo, float hi) {
    const unsigned ulo = __builtin_bit_cast(unsigned, lo) + 0x8000u;
    const unsigned uhi = __builtin_bit_cast(unsigned, hi) + 0x8000u;
    return (ulo >> 16) | (uhi & 0xFFFF0000u);
}

// ---- workspace layout (bytes) ----
#define WS_WU1 0        // 48 frags x 1KB = 49152
#define WS_WU2 49152    // 48 frags = 49152
#define WS_WD  98304    // 4 frags = 4096
#define WS_BDP 102400   // 32 f32
#define WS_DG  114688   // global D overflow region

// Weights pre-swizzled to MFMA B-frag order (frag f, lane l, elem e -> B[k=(l>>4)*8+e][n=l&15])
// and pre-scaled: i/f/o gates by log2e, L1 g-gate by 2*log2e, L2 g-gate (relu) raw.
// TRANSPOSE DUALITY (r7/r9): the same register bits serve as an A-frag of U^T, so
// z^T = mfma(wz, h_frag) and d^T = mfma(wd, h_frag) need NO new layouts.
// BIAS FOLDING (r5): b1 in wu1 kt2 row k=16 (activated by 1.0 in ax); b2 in wu2 kt0 row
// k=30 (activated by d[...,30]==1.0 via bdp[30]=1.0).
// wu1: A1=[h1(0:64)|x(16)|1|0...], kt0=U1[0:32], kt1=U1[32:64], kt2=[W1(16);b1;zeros(15)]
// wu2: A2=[d(0:30)|1|0|h2(0:64)], kt0=[W2(30);b2;0], kt1=U2[0:32], kt2=U2[32:64]
// wd : d = h1 @ Wd (cols padded 30->32, col30 forced to 1.0 via bdp), unscaled
__global__ void precompute(const float* __restrict__ W1, const float* __restrict__ U1,
                           const float* __restrict__ b1, const float* __restrict__ Wd,
                           const float* __restrict__ bd, const float* __restrict__ W2,
                           const float* __restrict__ U2, const float* __restrict__ b2,
                           short* __restrict__ wu1_sw, short* __restrict__ wu2_sw,
                           short* __restrict__ wd_sw, float* __restrict__ bdp) {
    const int lane = threadIdx.x;  // 64
    const int b = blockIdx.x;      // 101
    if (b < 48) {
        const int f = b, jt = f / 12, g = (f / 3) & 3, kt = f % 3;
        const int col = g * 64 + jt * 16 + (lane & 15);
        const float sc = (g == 2) ? TWO_LOG2E : LOG2E;
        for (int e = 0; e < 8; ++e) {
            const int sub = (lane >> 4) * 8 + e;  // 0..31
            float v;
            if (kt == 0)      v = U1[sub * G4H + col];
            else if (kt == 1) v = U1[(sub + 32) * G4H + col];
            else              v = (sub < 16) ? W1[sub * G4H + col]
                                             : ((sub == 16) ? b1[col] : 0.0f);
            wu1_sw[(f * 64 + lane) * 8 + e] = f2bf_rne(v * sc);
        }
    } else if (b < 96) {
        const int f = b - 48, jt = f / 12, g = (f / 3) & 3, kt = f % 3;
        const int col = g * 64 + jt * 16 + (lane & 15);
        const float sc = (g == 2) ? 1.0f : LOG2E;  // relu gate stays raw
        for (int e = 0; e < 8; ++e) {
            const int sub = (lane >> 4) * 8 + e;
            float v;
            if (kt == 0)      v = (sub < D_MLP) ? W2[sub * G4H + col]
                                                : ((sub == D_MLP) ? b2[col] : 0.0f);
            else if (kt == 1) v = U2[sub * G4H + col];
            else              v = U2[(sub + 32) * G4H + col];
            wu2_sw[(f * 64 + lane) * 8 + e] = f2bf_rne(v * sc);
        }
    } else if (b < 100) {
        const int fd = b - 96, nt = fd >> 1, kt = fd & 1;
        const int col = nt * 16 + (lane & 15);
        for (int e = 0; e < 8; ++e) {
            const int k = kt * 32 + (lane >> 4) * 8 + e;  // h1 dim 0..63
            const float v = (col < D_MLP) ? Wd[k * D_MLP + col] : 0.0f;
            wd_sw[(fd * 64 + lane) * 8 + e] = f2bf_rne(v);
        }
    } else {
        // bdp: dense bias cols 0..29; col 30 = 1.0 (phase-2 bias activator); col 31 = 0
        if (lane < 32)
            bdp[lane] = (lane < D_MLP) ? bd[lane] : ((lane == D_MLP) ? 1.0f : 0.0f);
    }
}

// ---------------- r10: D-SPLIT for 8 blocks/CU ----------------
// Occupancy matrix from r3/r6/r7/r9: VGPR tiers are {<=64: 8 waves/SIMD, <=128: 4} — no
// intermediate tier (m69). At VGPR=64 the binding cap was LDS (29696 -> 5 blocks/CU = 20
// waves). Fix: D[0..DLDS) stays in LDS, D[DLDS..9] goes to workspace (L2-class; r9 proved
// the global-D path exact + visible via the barrier's vmcnt drain). DLDS=5: LDS 19456 ->
// 8 blocks/CU = 32 waves/CU (+60% residency). Body = r9 verbatim, t<DLDS branch (uniform).
// DLDS=10 instantiation = pure-LDS fallback if ws too small.
// TRIPWIRES: occupancy >=50 but dur flat -> latency plateau is structural, declare; occupancy
// flat -> scratch-residency cap; regress -> revert DLDS=10.
template <int DLDS>
__global__ __launch_bounds__(256)
__attribute__((amdgpu_waves_per_eu(4, 8)))
void lstm_all_t(const float* __restrict__ x, const short* __restrict__ wu1_sw,
                const short* __restrict__ wu2_sw, const short* __restrict__ wd_sw,
                const float* __restrict__ bdp, const float* __restrict__ Wf,
                const float* __restrict__ bfin, short* __restrict__ Dg,
                float* __restrict__ out) {
    __shared__ __align__(16) short P[2][BTILE * PSTR];       // 9216 B
    __shared__ __align__(16) short Dl[DLDS][BTILE * DSTR];   // DLDS=5: 10240 B -> total 19456
    const int tid = threadIdx.x, lane = tid & 63, wave = tid >> 6;
    const int q = lane >> 4, n = lane & 15;
    const int b0 = blockIdx.x * BTILE;
    short* const dgb = Dg + (size_t)blockIdx.x * ((T_STEPS - DLDS) * BTILE * DSTR);

    // ---- phase-1 weights: wave owns gate-col slice [g*64 + wave*16, +16) ----
    short8 wz[4][3];
#pragma unroll
    for (int g = 0; g < 4; ++g)
#pragma unroll
        for (int kt = 0; kt < 3; ++kt)
            wz[g][kt] = ((const short8*)wu1_sw)[(wave * 12 + g * 3 + kt) * 64 + lane];

    // d-projection: wave -> (row-tile mw, col-tile ntw). Transposed output -> per-jj bias.
    const int mw = (wave >> 1) & 1, ntw = wave & 1;
    const float4 bdvv = *(const float4*)&bdp[ntw * 16 + q * 4];

    // bias activator for the ax frag: lanes 32..47 (q==2) elem0 = bf16(1.0), else 0
    const unsigned bias0 = (lane >= 32 && lane < 48) ? 0x00003F80u : 0u;
    const bool hb = (lane >= 32);

    for (int i = tid; i < BTILE * PSTR; i += 256) P[0][i] = 0;

    float4_t cc[2];
    cc[0] = (float4_t){0, 0, 0, 0};
    cc[1] = (float4_t){0, 0, 0, 0};

    // x loads, lane-packed: lane<32 -> m=0 rows (b0+n), lane>=32 -> m=1 rows (b0+16+n)
    const float* xlane = x + (size_t)(b0 + (lane >> 5) * 16 + n) * (T_STEPS * D_IN)
                           + ((lane >> 4) & 1) * 8;
    float4 px0 = *(const float4*)xlane;
    float4 px1 = *(const float4*)(xlane + 4);
    __syncthreads();  // P[0] zeros visible

    // ================= phase 1: LSTM1 (tanh) + Dense into Dl/Dg =================
    for (int t = 0; t < T_STEPS; ++t) {
        const short* cb = P[t & 1];
        short* nb = P[(t & 1) ^ 1];

        // wd frags: opaque pointer defeats LICM -> re-loaded each t (L2-hot), short live range
        const short8* wp = (const short8*)wd_sw + (ntw * 2) * 64 + lane;
        asm volatile("" : "+v"(wp));
        const short8 wda = wp[0];
        const short8 wdb = wp[64];

        // x frags; lanes>=32 masked to the bias pattern (1.0 at k=16 for q==2)
        uint4 axu;
        axu.x = pk2bf(px0.x, px0.y);
        axu.y = pk2bf(px0.z, px0.w);
        axu.z = pk2bf(px1.x, px1.y);
        axu.w = pk2bf(px1.z, px1.w);
        uint4 axv;
        axv.x = __shfl_xor((int)axu.x, 32);
        axv.y = __shfl_xor((int)axu.y, 32);
        axv.z = __shfl_xor((int)axu.z, 32);
        axv.w = __shfl_xor((int)axu.w, 32);
        const uint4 bmask = (uint4){bias0, 0u, 0u, 0u};
        short8 axm[2];
        axm[0] = __builtin_bit_cast(short8, hb ? bmask : axu);
        axm[1] = __builtin_bit_cast(short8, hb ? bmask : axv);

        const int tn = (t + 1 < T_STEPS) ? t + 1 : T_STEPS - 1;
        px0 = *(const float4*)(xlane + tn * D_IN);
        px1 = *(const float4*)(xlane + tn * D_IN + 4);

#pragma unroll
        for (int m = 0; m < 2; ++m) {
            const int arow = (16 * m + n) * PSTR + q * 8;
            const short8 ah0 = *(const short8*)&cb[arow];
            const short8 ah1 = *(const short8*)&cb[arow + 32];
            float4_t ac[4];
#pragma unroll
            for (int g = 0; g < 4; ++g) {
                // SWAPPED: ac[g][jj] = gate g of cell (batch=16m+n, hcol=wave*16+q*4+jj)
                float4_t c = (float4_t){0, 0, 0, 0};
                c = mfma16(wz[g][0], ah0, c);
                c = mfma16(wz[g][1], ah1, c);
                c = mfma16(wz[g][2], axm[m], c);   // includes +b1 via k=16
                ac[g] = c;
            }
            // merged-rcp activation: 5 exp2 + 2 rcp per cell.
            float hv[4];
#pragma unroll
            for (int jj = 0; jj < 4; ++jj) {
                const float Bv = __builtin_amdgcn_exp2f(-ac[0][jj]);
                const float Fv = __builtin_amdgcn_exp2f(-ac[1][jj]);
                const float Qv = __builtin_amdgcn_exp2f(ac[2][jj]);
                const float Av = __builtin_amdgcn_exp2f(-ac[3][jj]);
                const float uu = (1.0f + Bv) * (Qv + 1.0f);
                const float vv = 1.0f + Fv;
                const float num = cc[m][jj] * uu + (Qv - 1.0f) * vv;
                const float cn = num * __builtin_amdgcn_rcpf(uu * vv);
                cc[m][jj] = cn;
                const float Pv = __builtin_amdgcn_exp2f(cn * TWO_LOG2E);
                const float ww = (1.0f + Av) * (Pv + 1.0f);
                hv[jj] = (Pv - 1.0f) * __builtin_amdgcn_rcpf(ww);
            }
            *(uint2*)&nb[(16 * m + n) * PSTR + wave * 16 + q * 4] =
                (uint2){pk2bf(hv[0], hv[1]), pk2bf(hv[2], hv[3])};
        }
        __syncthreads();  // h1_t complete

        // d_t^T = mfma(wd, h) (transpose duality). Thread holds d-cols ntw*16+q*4..+3 of
        // batch row 16mw+n -> one 8B store; t<DLDS -> LDS, else workspace (coalesced dwordx2).
        // dcol 30 gets 0 + 1.0 (bdvv) -> exact bf16 1.0: the phase-2 bias activator.
        {
            const int drow = (16 * mw + n) * PSTR + q * 8;
            const short8 dh0 = *(const short8*)&nb[drow];
            const short8 dh1 = *(const short8*)&nb[drow + 32];
            float4_t dd = (float4_t){bdvv.x, bdvv.y, bdvv.z, bdvv.w};
            dd = mfma16(wda, dh0, dd);
            dd = mfma16(wdb, dh1, dd);
            const uint2 dpk = (uint2){pk2bf(dd[0], dd[1]), pk2bf(dd[2], dd[3])};
            const int doff = (16 * mw + n) * DSTR + ntw * 16 + q * 4;
            if (t < DLDS)
                *(uint2*)&Dl[t][doff] = dpk;
            else
                *(uint2*)&dgb[(t - DLDS) * (BTILE * DSTR) + doff] = dpk;
        }
    }

    // ================= phase boundary =================
    __syncthreads();  // drains Dg stores (vmcnt) + all P reads before re-zeroing
#pragma unroll
    for (int g = 0; g < 4; ++g)
#pragma unroll
        for (int kt = 0; kt < 3; ++kt)
            wz[g][kt] = ((const short8*)wu2_sw)[(wave * 12 + g * 3 + kt) * 64 + lane];
    cc[0] = (float4_t){0, 0, 0, 0};
    cc[1] = (float4_t){0, 0, 0, 0};
    for (int i = tid; i < BTILE * PSTR; i += 256) P[0][i] = 0;
    __syncthreads();

    // ================= phase 2: LSTM2 (relu) from Dl/Dg =================
    for (int t = 0; t < T_STEPS; ++t) {
        const short* cb = P[t & 1];
        short* nb = P[(t & 1) ^ 1];

        // both m rows' d frags issued together (16B/lane, LDS or L2-hot coalesced)
        uint4 adu0, adu1;
        if (t < DLDS) {
            adu0 = *(const uint4*)&Dl[t][n * DSTR + q * 8];
            adu1 = *(const uint4*)&Dl[t][(16 + n) * DSTR + q * 8];
        } else {
            const short* dgt = dgb + (t - DLDS) * (BTILE * DSTR);
            adu0 = *(const uint4*)&dgt[n * DSTR + q * 8];
            adu1 = *(const uint4*)&dgt[(16 + n) * DSTR + q * 8];
        }
        short8 adm[2];
        adm[0] = __builtin_bit_cast(short8, adu0);
        adm[1] = __builtin_bit_cast(short8, adu1);

#pragma unroll
        for (int m = 0; m < 2; ++m) {
            const int ar = 16 * m + n;
            const short8 ah0 = *(const short8*)&cb[ar * PSTR + q * 8];
            const short8 ah1 = *(const short8*)&cb[ar * PSTR + 32 + q * 8];
            float4_t ac[4];
#pragma unroll
            for (int g = 0; g < 4; ++g) {
                float4_t c = (float4_t){0, 0, 0, 0};
                c = mfma16(wz[g][0], adm[m], c);   // includes +b2 via dcol30==1.0 x W2 row30
                c = mfma16(wz[g][1], ah0, c);
                c = mfma16(wz[g][2], ah1, c);
                ac[g] = c;
            }
            // single-rcp relu activation (r8-validated): 3 exp2 + 1 rcp per cell.
            float hv[4];
#pragma unroll
            for (int jj = 0; jj < 4; ++jj) {
                const float Bv = __builtin_amdgcn_exp2f(-ac[0][jj]);
                const float Fv = __builtin_amdgcn_exp2f(-ac[1][jj]);
                const float gp = fmaxf(ac[2][jj], 0.0f);
                const float Av = __builtin_amdgcn_exp2f(-ac[3][jj]);
                const float eb = 1.0f + Bv, ef = 1.0f + Fv, ea = 1.0f + Av;
                const float num = cc[m][jj] * eb + gp * ef;
                const float R = __builtin_amdgcn_rcpf(eb * ef * ea);
                cc[m][jj] = num * ea * R;
                hv[jj] = fmaxf(num, 0.0f) * R;
            }
            *(uint2*)&nb[ar * PSTR + wave * 16 + q * 4] =
                (uint2){pk2bf(hv[0], hv[1]), pk2bf(hv[2], hv[3])};
        }
        __syncthreads();
    }

    // ---- out = h2_9 @ Wf + bf ; t=9 wrote nb = P[0] ----
    if (tid < 128) {
        const int r = tid >> 2, c = tid & 3;
        float s = bfin[c];
#pragma unroll
        for (int kb = 0; kb < 8; ++kb) {
            const short8 h8 = *(const short8*)&P[0][r * PSTR + kb * 8];
#pragma unroll
            for (int e = 0; e < 8; ++e)
                s += bf2f(h8[e]) * Wf[(kb * 8 + e) * D_OUT + c];
        }
        out[(size_t)(b0 + r) * D_OUT + c] = s;
    }
}

extern "C" void kernel_launch(void* const* d_in, const int* in_sizes, int n_in,
                              void* d_out, int out_size, void* d_ws, size_t ws_size,
                              hipStream_t stream) {
    const float* x  = (const float*)d_in[0];
    const float* W1 = (const float*)d_in[1];
    const float* U1 = (const float*)d_in[2];
    const float* b1 = (const float*)d_in[3];
    const float* Wd = (const float*)d_in[4];
    const float* bd = (const float*)d_in[5];
    const float* W2 = (const float*)d_in[6];
    const float* U2 = (const float*)d_in[7];
    const float* b2 = (const float*)d_in[8];
    const float* Wf = (const float*)d_in[9];
    const float* bf = (const float*)d_in[10];
    float* out = (float*)d_out;

    char* ws = (char*)d_ws;
    short* wu1_sw = (short*)(ws + WS_WU1);
    short* wu2_sw = (short*)(ws + WS_WU2);
    short* wd_sw  = (short*)(ws + WS_WD);
    float* bdp    = (float*)(ws + WS_BDP);

    precompute<<<101, 64, 0, stream>>>(W1, U1, b1, Wd, bd, W2, U2, b2,
                                       wu1_sw, wu2_sw, wd_sw, bdp);

    // DLDS=5: D[5..9] in workspace: (10-5)*32*32*2 B = 10240 B per block x 2048 blocks
    const size_t dg_need = (size_t)(T_STEPS - 5) * BTILE * DSTR * 2 * (B_TOT / BTILE);
    if (ws_size >= (size_t)WS_DG + dg_need) {
        short* Dg = (short*)(ws + WS_DG);
        lstm_all_t<5><<<B_TOT / BTILE, 256, 0, stream>>>(x, wu1_sw, wu2_sw, wd_sw,
                                                         bdp, Wf, bf, Dg, out);
    } else {
        lstm_all_t<T_STEPS><<<B_TOT / BTILE, 256, 0, stream>>>(x, wu1_sw, wu2_sw, wd_sw,
                                                               bdp, Wf, bf, (short*)ws, out);
    }
}